// Round 4
// baseline (2577.478 us; speedup 1.0000x reference)
//
#include <hip/hip_runtime.h>
#include <stddef.h>

typedef unsigned short u16;
typedef unsigned int u32;

#define B_ 4
#define T_ 2048
#define C_ 1024
#define E_ 8
#define H_ 4096
#define NTOK (B_ * T_)     // 8192
#define NPAIR (NTOK * 2)   // 16384
#define BM 128
#define BN 128
#define BK 64              // k-tile (bf16 elements); row = 128 B
#define MAXTILES 136       // ceil((16384 + 8*127)/128)
#define MAXROWS (MAXTILES * 128)  // 17408

typedef __bf16 bf16x8 __attribute__((ext_vector_type(8)));
typedef float f32x4 __attribute__((ext_vector_type(4)));

__device__ __forceinline__ u16 f2bf(float f) {
    union { float f; u32 u; } c;
    c.f = f;
    u32 r = c.u + 0x7FFFu + ((c.u >> 16) & 1u);  // round-to-nearest-even
    return (u16)(r >> 16);
}

// ---------------- LayerNorm: h = bf16(LN(x)), out = x ----------------
__global__ __launch_bounds__(256) void ln_kernel(
    const float* __restrict__ x, const float* __restrict__ gamma,
    const float* __restrict__ beta, float* __restrict__ out,
    u16* __restrict__ h) {
    const int token = blockIdx.x;
    const int t = threadIdx.x;
    const float* xr = x + (size_t)token * C_;
    float4 v = *(const float4*)(xr + t * 4);
    float s = v.x + v.y + v.z + v.w;
    float ss = v.x * v.x + v.y * v.y + v.z * v.z + v.w * v.w;
    #pragma unroll
    for (int off = 32; off > 0; off >>= 1) {
        s += __shfl_down(s, off);
        ss += __shfl_down(ss, off);
    }
    __shared__ float ws_s[4], ws_q[4];
    const int wave = t >> 6, lane = t & 63;
    if (lane == 0) { ws_s[wave] = s; ws_q[wave] = ss; }
    __syncthreads();
    float S = ws_s[0] + ws_s[1] + ws_s[2] + ws_s[3];
    float Q = ws_q[0] + ws_q[1] + ws_q[2] + ws_q[3];
    float mu = S * (1.0f / C_);
    float var = Q * (1.0f / C_) - mu * mu;
    float rstd = rsqrtf(var + 1e-5f);
    float4 g = *(const float4*)(gamma + t * 4);
    float4 b = *(const float4*)(beta + t * 4);
    ushort4 hv;
    hv.x = f2bf((v.x - mu) * rstd * g.x + b.x);
    hv.y = f2bf((v.y - mu) * rstd * g.y + b.y);
    hv.z = f2bf((v.z - mu) * rstd * g.z + b.z);
    hv.w = f2bf((v.w - mu) * rstd * g.w + b.w);
    *(float4*)(out + (size_t)token * C_ + t * 4) = v;  // out = x (residual base)
    *(ushort4*)(h + (size_t)token * C_ + t * 4) = hv;
}

// ---------------- Weight convert+transpose: fp32 [E][K][N] -> bf16 [E][N][K] --
// PERM: source k-row permuted per 64-block by phi(r)=((r&3)<<4)|(r>>2), matching
// the gemm1 epilogue's packed hidden layout (only used for W2).
template <bool PERM>
__global__ __launch_bounds__(256) void convert_transpose(
    const float* __restrict__ in, u16* __restrict__ outp, int K, int N) {
    const int e = blockIdx.z;
    const int k0 = blockIdx.y * 64, n0 = blockIdx.x * 64;
    const int tx = threadIdx.x & 15, ty = threadIdx.x >> 4;  // 16 x 16
    __shared__ float t[64][69];  // pitch 69: 2-way max bank aliasing on reads
    const float* src = in + (size_t)e * K * N;
    u16* dst = outp + (size_t)e * N * K;
    #pragma unroll
    for (int i = 0; i < 4; ++i) {
        int r = ty + i * 16;  // LDS row (= dst k-offset)
        int kr = PERM ? (((r & 3) << 4) | (r >> 2)) : r;  // src k-offset
        float4 v = *(const float4*)(src + (size_t)(k0 + kr) * N + n0 + tx * 4);
        t[r][tx * 4 + 0] = v.x;
        t[r][tx * 4 + 1] = v.y;
        t[r][tx * 4 + 2] = v.z;
        t[r][tx * 4 + 3] = v.w;
    }
    __syncthreads();
    #pragma unroll
    for (int i = 0; i < 4; ++i) {
        int nl = ty + i * 16;
        ushort4 o;
        o.x = f2bf(t[tx * 4 + 0][nl]);
        o.y = f2bf(t[tx * 4 + 1][nl]);
        o.z = f2bf(t[tx * 4 + 2][nl]);
        o.w = f2bf(t[tx * 4 + 3][nl]);
        *(ushort4*)(dst + (size_t)(n0 + nl) * K + k0 + tx * 4) = o;
    }
}

// ---------------- Expert bucketing (LDS-aggregated atomics) ----------------
__global__ __launch_bounds__(256) void count_kernel(
    const int* __restrict__ winners, int* __restrict__ counts) {
    __shared__ int c[E_];
    if (threadIdx.x < E_) c[threadIdx.x] = 0;
    __syncthreads();
    int p = blockIdx.x * 256 + threadIdx.x;
    atomicAdd(&c[winners[p]], 1);
    __syncthreads();
    if (threadIdx.x < E_) atomicAdd(&counts[threadIdx.x], c[threadIdx.x]);
}

__global__ void offsets_kernel(const int* __restrict__ counts, int* __restrict__ padded_off,
                               int* __restrict__ tile_expert) {
    if (threadIdx.x != 0 || blockIdx.x != 0) return;
    int off = 0;
    padded_off[0] = 0;
    int po[E_ + 1];
    po[0] = 0;
    for (int e = 0; e < E_; ++e) {
        off += ((counts[e] + 127) >> 7) << 7;
        po[e + 1] = off;
        padded_off[e + 1] = off;
    }
    for (int t = 0; t < MAXTILES; ++t) {
        int r = t * 128;
        int e = -1;
        if (r < off) {
            e = 0;
            while (r >= po[e + 1]) ++e;
        }
        tile_expert[t] = e;
    }
}

__global__ __launch_bounds__(256) void place_kernel(
    const int* __restrict__ winners, const float* __restrict__ wts,
    const int* __restrict__ padded_off, int* __restrict__ pos,
    int* __restrict__ token_id, float* __restrict__ pair_w) {
    __shared__ int cnt[E_], base[E_];
    if (threadIdx.x < E_) cnt[threadIdx.x] = 0;
    __syncthreads();
    int p = blockIdx.x * 256 + threadIdx.x;
    int e = winners[p];
    int lrank = atomicAdd(&cnt[e], 1);
    __syncthreads();
    if (threadIdx.x < E_)
        base[threadIdx.x] = atomicAdd(&pos[threadIdx.x], cnt[threadIdx.x]);
    __syncthreads();
    int slot = padded_off[e] + base[e] + lrank;
    token_id[slot] = p >> 1;
    pair_w[slot] = wts[p];
}

// ---------------- Grouped GEMM, register-prefetch pipelined ---------
// PHASE2=false: hidden[r,:] = bf16(relu(h[tok(r)] @ W1T[e]^T)^2)  K=1024, N=4096
//               hidden K-dim stored permuted: p64 = lrow*4 + ni
// PHASE2=true : out[tok(r),:] += pair_w[r] * (hidden[r] @ W2T[e]^T) K=4096, N=1024
// B operand (Bmat) is pre-transposed bf16 [E][N][K] (W2T rows phi-permuted).
// Pipeline: regs hold tile k+1 (global loads issued during tile k's MFMA);
// ds_write at top of each iter. Exposed HBM latency ~0 instead of full.
template <bool PHASE2>
__global__ __launch_bounds__(256, 3) void gemm_kernel(
    const u16* __restrict__ Amat, const u16* __restrict__ Bmat,
    const int* __restrict__ token_id, const float* __restrict__ pair_w,
    const int* __restrict__ tile_expert, u16* __restrict__ hidden,
    float* __restrict__ out) {
    constexpr int Kdim = PHASE2 ? H_ : C_;
    constexpr int Ndim = PHASE2 ? C_ : H_;
    const int ct = blockIdx.x;
    const int rt = blockIdx.y;
    const int e = tile_expert[rt];
    if (e < 0) return;
    const int tid = threadIdx.x;
    const int w = tid >> 6;      // wave 0..3
    const int lane = tid & 63;
    const int n0 = ct * BN;
    const u16* Bb = Bmat + (size_t)e * Ndim * Kdim;

    __shared__ u16 As[BM * BK];  // 16 KB, [row][k], row = 128 B
    __shared__ u16 Bs[BN * BK];  // 16 KB, [n][k]

    // Staging geometry (same as gld16 version): per wave, 4 slots x (8 rows x
    // 128 B) = 32 rows.  Lane i -> row sub = i>>3, k-chunk (16 B) =
    // (i&7) ^ sub  (XOR swizzle on the global side; LDS side is lane*16).
    const int sub = lane >> 3;
    const size_t koffB = (size_t)(((lane & 7) ^ sub) * 16);

    const char* abase[4];
    bool aval[4];
    const char* bbase[4];
    u16* adst[4];
    u16* bdst[4];
    #pragma unroll
    for (int j = 0; j < 4; ++j) {
        const int lrow32 = w * 32 + j * 8 + sub;
        const int grow = rt * BM + lrow32;
        if (PHASE2) {
            aval[j] = true;
            abase[j] = (const char*)(Amat + (size_t)grow * Kdim) + koffB;
        } else {
            int tok = token_id[grow];
            aval[j] = tok >= 0;
            abase[j] = (const char*)(Amat + (size_t)(tok < 0 ? 0 : tok) * Kdim) + koffB;
        }
        bbase[j] = (const char*)(Bb + (size_t)(n0 + lrow32) * Kdim) + koffB;
        adst[j] = &As[(w * 32 + j * 8) * BK] + lane * 8;  // lane's 16 B slot
        bdst[j] = &Bs[(w * 32 + j * 8) * BK] + lane * 8;
    }

    const int wr = w >> 1, wc = w & 1;
    const int lrow = lane & 15;
    const int quad = lane >> 4;
    const int rsw = lrow & 7;  // read-side swizzle key

    f32x4 acc[4][4] = {};
    uint4 ra[4], rb[4];
    const uint4 z4 = {0u, 0u, 0u, 0u};

    // preload tile 0 into registers
    #pragma unroll
    for (int j = 0; j < 4; ++j) {
        ra[j] = aval[j] ? *(const uint4*)(abase[j]) : z4;
        rb[j] = *(const uint4*)(bbase[j]);
    }

    for (int k0 = 0; k0 < Kdim; k0 += BK) {
        __syncthreads();  // all waves done reading LDS (previous tile)
        #pragma unroll
        for (int j = 0; j < 4; ++j) {
            *(uint4*)adst[j] = ra[j];
            *(uint4*)bdst[j] = rb[j];
        }
        __syncthreads();  // LDS writes visible
        // issue next tile's global loads; they fly during this tile's MFMA
        if (k0 + BK < Kdim) {
            const size_t kb = (size_t)(k0 + BK) * 2;
            #pragma unroll
            for (int j = 0; j < 4; ++j) {
                ra[j] = aval[j] ? *(const uint4*)(abase[j] + kb) : z4;
                rb[j] = *(const uint4*)(bbase[j] + kb);
            }
        }
        #pragma unroll
        for (int kk = 0; kk < 2; ++kk) {
            bf16x8 af[4], bfv[4];
            #pragma unroll
            for (int mi = 0; mi < 4; ++mi) {
                int row = wr * 64 + mi * 16 + lrow;
                int pch = (kk * 4 + quad) ^ rsw;
                af[mi] = *(const bf16x8*)&As[row * BK + pch * 8];
            }
            #pragma unroll
            for (int ni = 0; ni < 4; ++ni) {
                int row = wc * 64 + ni * 16 + lrow;
                int pch = (kk * 4 + quad) ^ rsw;
                bfv[ni] = *(const bf16x8*)&Bs[row * BK + pch * 8];
            }
            #pragma unroll
            for (int mi = 0; mi < 4; ++mi)
                #pragma unroll
                for (int ni = 0; ni < 4; ++ni)
                    acc[mi][ni] = __builtin_amdgcn_mfma_f32_16x16x32_bf16(
                        af[mi], bfv[ni], acc[mi][ni], 0, 0, 0);
        }
    }

    if (!PHASE2) {
        // Packed store: per (mi,j)-row, lane's 4 ni-values go to permuted
        // k' = n0 + wc*64 + lrow*4 + ni  -> one ushort4 (8 B) store.
        #pragma unroll
        for (int mi = 0; mi < 4; ++mi) {
            int rbase = rt * BM + wr * 64 + mi * 16 + quad * 4;
            #pragma unroll
            for (int j = 0; j < 4; ++j) {
                ushort4 o;
                float v0 = fmaxf(acc[mi][0][j], 0.0f);
                float v1 = fmaxf(acc[mi][1][j], 0.0f);
                float v2 = fmaxf(acc[mi][2][j], 0.0f);
                float v3 = fmaxf(acc[mi][3][j], 0.0f);
                o.x = f2bf(v0 * v0);
                o.y = f2bf(v1 * v1);
                o.z = f2bf(v2 * v2);
                o.w = f2bf(v3 * v3);
                *(ushort4*)&hidden[(size_t)(rbase + j) * H_ + n0 + wc * 64 + lrow * 4] = o;
            }
        }
    } else {
        #pragma unroll
        for (int mi = 0; mi < 4; ++mi) {
            int rbase = rt * BM + wr * 64 + mi * 16 + quad * 4;
            #pragma unroll
            for (int j = 0; j < 4; ++j) {
                int grow = rbase + j;
                int tok = token_id[grow];
                if (tok < 0) continue;
                float pw = pair_w[grow];
                #pragma unroll
                for (int ni = 0; ni < 4; ++ni) {
                    int col = n0 + wc * 64 + ni * 16 + lrow;
                    atomicAdd(&out[(size_t)tok * C_ + col], pw * acc[mi][ni][j]);
                }
            }
        }
    }
}

// ---------------- Launch ----------------
extern "C" void kernel_launch(void* const* d_in, const int* in_sizes, int n_in,
                              void* d_out, int out_size, void* d_ws, size_t ws_size,
                              hipStream_t stream) {
    const float* x = (const float*)d_in[0];
    const float* weights = (const float*)d_in[1];
    const float* gamma = (const float*)d_in[2];
    const float* beta = (const float*)d_in[3];
    const float* W1 = (const float*)d_in[4];
    const float* W2 = (const float*)d_in[5];
    const int* winners = (const int*)d_in[6];
    float* out = (float*)d_out;

    char* ws = (char*)d_ws;
    const size_t SZ_H = (size_t)NTOK * C_ * 2;           // 16 MB
    const size_t SZ_HID = (size_t)MAXROWS * H_ * 2;      // 136 MB
    const size_t SZ_WT = (size_t)E_ * H_ * C_ * 2;       // 64 MB each
    const size_t OFF_HID = SZ_H;
    const size_t OFF_W1T = OFF_HID + SZ_HID;
    const size_t OFF_W2T = OFF_W1T + SZ_WT;
    const size_t OFF_META = OFF_W2T + SZ_WT;

    u16* h = (u16*)ws;
    u16* hidden = (u16*)(ws + OFF_HID);
    u16* W1T = (u16*)(ws + OFF_W1T);
    u16* W2T = (u16*)(ws + OFF_W2T);
    int* meta = (int*)(ws + OFF_META);
    int* counts = meta;            // [0,8)
    int* pos = meta + 8;           // [8,16)
    int* padded_off = meta + 16;   // [16,32)
    int* tile_expert = meta + 48;  // [48,184)
    int* token_id = meta + 192;
    float* pair_w = (float*)(meta + 192 + MAXROWS);

    hipMemsetAsync(meta, 0, 192 * sizeof(int), stream);
    hipMemsetAsync(token_id, 0xFF, (size_t)MAXROWS * sizeof(int), stream);

    ln_kernel<<<NTOK, 256, 0, stream>>>(x, gamma, beta, out, h);
    count_kernel<<<NPAIR / 256, 256, 0, stream>>>(winners, counts);
    convert_transpose<false><<<dim3(H_ / 64, C_ / 64, E_), 256, 0, stream>>>(W1, W1T, C_, H_);
    convert_transpose<true><<<dim3(C_ / 64, H_ / 64, E_), 256, 0, stream>>>(W2, W2T, H_, C_);
    offsets_kernel<<<1, 64, 0, stream>>>(counts, padded_off, tile_expert);
    place_kernel<<<NPAIR / 256, 256, 0, stream>>>(winners, weights, padded_off, pos,
                                                  token_id, pair_w);
    gemm_kernel<false><<<dim3(H_ / BN, MAXTILES), 256, 0, stream>>>(
        h, W1T, token_id, pair_w, tile_expert, hidden, nullptr);
    gemm_kernel<true><<<dim3(C_ / BN, MAXTILES), 256, 0, stream>>>(
        hidden, W2T, token_id, pair_w, tile_expert, nullptr, out);
}